// Round 1
// baseline (1452.637 us; speedup 1.0000x reference)
//
#include <hip/hip_runtime.h>
#include <cstddef>

// Problem constants
#define B   32
#define C   16
#define H   64
#define D   256
#define K   2048
#define T   15
#define PAD 7
#define EPS 1e-5

#define BH      (B*H)       // 2048
#define ROWS    (B*C*H)     // 32768 VQ rows
#define N_PER_CH ((double)(B*H*D)) // 524288

// ---------------------------------------------------------------------------
// K1: encoder conv (f64) + per-block partial sums for BN stats (deterministic)
// grid = BH blocks, 256 threads (one thread per d)
// ---------------------------------------------------------------------------
__global__ __launch_bounds__(256) void k1_conv_stats(
    const float* __restrict__ x, const float* __restrict__ w,
    double* __restrict__ partial /* [BH][C][2] */) {
  __shared__ float xs[D + 2*PAD];
  __shared__ float wsm[C*T];
  __shared__ double red[4][C][2];
  const int bh  = blockIdx.x;
  const int tid = threadIdx.x;
  const float* xrow = x + (size_t)bh * D;
  if (tid < C*T) wsm[tid] = w[tid];
  xs[tid + PAD] = xrow[tid];
  if (tid < PAD) { xs[tid] = 0.f; xs[tid + PAD + D] = 0.f; }
  __syncthreads();
  const int d = tid;
#pragma unroll
  for (int c = 0; c < C; c++) {
    double z = 0.0;
#pragma unroll
    for (int t = 0; t < T; t++)
      z = fma((double)wsm[c*T + t], (double)xs[d + t], z);
    double zz = z * z;
#pragma unroll
    for (int off = 32; off; off >>= 1) {
      z  += __shfl_down(z,  off, 64);
      zz += __shfl_down(zz, off, 64);
    }
    if ((tid & 63) == 0) { red[tid >> 6][c][0] = z; red[tid >> 6][c][1] = zz; }
  }
  __syncthreads();
  if (tid < C*2) {
    int c = tid >> 1, j = tid & 1;
    double v = red[0][c][j] + red[1][c][j] + red[2][c][j] + red[3][c][j];
    partial[(size_t)bh * (C*2) + c*2 + j] = v;
  }
}

// ---------------------------------------------------------------------------
// K2: finalize BN per-channel params (deterministic tree). grid=C, 256 thr
// params[c][4] = m, v, a = gamma*rsqrt(v+eps), b = beta - a*m   (f64)
// ---------------------------------------------------------------------------
__global__ __launch_bounds__(256) void k2_stats_final(
    const double* __restrict__ partial, const float* __restrict__ gamma,
    const float* __restrict__ beta, double* __restrict__ params) {
  __shared__ double rs[256], rq[256];
  const int c = blockIdx.x;
  const int tid = threadIdx.x;
  double s = 0.0, q = 0.0;
  for (int i = tid; i < BH; i += 256) {
    s += partial[(size_t)i * (C*2) + c*2 + 0];
    q += partial[(size_t)i * (C*2) + c*2 + 1];
  }
  rs[tid] = s; rq[tid] = q;
  __syncthreads();
  for (int off = 128; off; off >>= 1) {
    if (tid < off) { rs[tid] += rs[tid + off]; rq[tid] += rq[tid + off]; }
    __syncthreads();
  }
  if (tid == 0) {
    double m = rs[0] / N_PER_CH;
    double v = rq[0] / N_PER_CH - m * m;
    double a = (double)gamma[c] / sqrt(v + EPS);
    double b = (double)beta[c] - a * m;
    params[c*4+0] = m; params[c*4+1] = v; params[c*4+2] = a; params[c*4+3] = b;
  }
}

// ---------------------------------------------------------------------------
// K6: ||e_k||^2 in f64 (+f32 copy). grid=K blocks, 64 threads
// ---------------------------------------------------------------------------
__global__ __launch_bounds__(64) void k6_enorm(
    const float* __restrict__ emb, double* __restrict__ enorm,
    float* __restrict__ enormf) {
  const int k = blockIdx.x;
  const int tid = threadIdx.x;
  const float* er = emb + (size_t)k * D;
  double s = 0.0;
  for (int i = tid; i < D; i += 64) { double e = (double)er[i]; s = fma(e, e, s); }
#pragma unroll
  for (int off = 32; off; off >>= 1) s += __shfl_down(s, off, 64);
  if (tid == 0) { enorm[k] = s; enormf[k] = (float)s; }
}

// ---------------------------------------------------------------------------
// K3: recompute conv (f64) + affine -> z_e (f32) into d_out. grid=BH, 256 thr
// ---------------------------------------------------------------------------
__global__ __launch_bounds__(256) void k3_ze(
    const float* __restrict__ x, const float* __restrict__ w,
    const double* __restrict__ params, float* __restrict__ zE) {
  __shared__ float xs[D + 2*PAD];
  __shared__ float wsm[C*T];
  const int bh  = blockIdx.x;
  const int b = bh >> 6, h = bh & 63;
  const int tid = threadIdx.x;
  const float* xrow = x + (size_t)bh * D;
  if (tid < C*T) wsm[tid] = w[tid];
  xs[tid + PAD] = xrow[tid];
  if (tid < PAD) { xs[tid] = 0.f; xs[tid + PAD + D] = 0.f; }
  __syncthreads();
  const int d = tid;
#pragma unroll
  for (int c = 0; c < C; c++) {
    double z = 0.0;
#pragma unroll
    for (int t = 0; t < T; t++)
      z = fma((double)wsm[c*T + t], (double)xs[d + t], z);
    double ze = fma(params[c*4+2], z, params[c*4+3]);
    zE[(((size_t)b*C + c)*H + h)*D + d] = (float)ze;
  }
}

// ---------------------------------------------------------------------------
// K4: phase-A f32 GEMM criterion + per-thread top-2 candidates.
// Block tile: 128 rows x 128 k, 256 threads (16x16), 8x8 per-thread regs.
// grid = ROWS/128 = 256 blocks.
// ---------------------------------------------------------------------------
__global__ __launch_bounds__(256) void k4_phaseA(
    const float* __restrict__ zE, const float* __restrict__ emb,
    const float* __restrict__ enormf, int* __restrict__ cand /*[ROWS][32]*/) {
  __shared__ float zsh[128][34];
  __shared__ float esh[128][34];
  __shared__ float ensh[128];
  const int tid = threadIdx.x;
  const int tx = tid & 15, ty = tid >> 4;
  const int row0 = blockIdx.x * 128;
  float v0[8], v1[8]; int i0[8], i1[8];
#pragma unroll
  for (int j = 0; j < 8; j++) { v0[j] = 3.0e38f; v1[j] = 3.0e38f; i0[j] = 0; i1[j] = 0; }

  for (int kt = 0; kt < K; kt += 128) {
    float acc[8][8];
#pragma unroll
    for (int a = 0; a < 8; a++)
#pragma unroll
      for (int b = 0; b < 8; b++) acc[a][b] = 0.f;

    for (int dc = 0; dc < D; dc += 32) {
      __syncthreads();
      if (dc == 0 && tid < 128) ensh[tid] = enormf[kt + tid];
#pragma unroll
      for (int i = 0; i < 4; i++) {
        int l = tid + 256*i;
        int r = l >> 3, q = (l & 7) * 4;
        const float4 fz = *(const float4*)(zE + (size_t)(row0 + r)*D + dc + q);
        zsh[r][q+0] = fz.x; zsh[r][q+1] = fz.y; zsh[r][q+2] = fz.z; zsh[r][q+3] = fz.w;
        const float4 fe = *(const float4*)(emb + (size_t)(kt + r)*D + dc + q);
        esh[r][q+0] = fe.x; esh[r][q+1] = fe.y; esh[r][q+2] = fe.z; esh[r][q+3] = fe.w;
      }
      __syncthreads();
#pragma unroll
      for (int dd = 0; dd < 32; dd++) {
        float zr[8], er[8];
#pragma unroll
        for (int j = 0; j < 8; j++) { zr[j] = zsh[ty*8 + j][dd]; er[j] = esh[tx*8 + j][dd]; }
#pragma unroll
        for (int a = 0; a < 8; a++)
#pragma unroll
          for (int b = 0; b < 8; b++) acc[a][b] = fmaf(zr[a], er[b], acc[a][b]);
      }
    }
    // epilogue: criterion + top-2 per row (per-thread k-subset)
#pragma unroll
    for (int b = 0; b < 8; b++) {
      float en = ensh[tx*8 + b];
      int k = kt + tx*8 + b;
#pragma unroll
      for (int a = 0; a < 8; a++) {
        float cv = fmaf(-2.f, acc[a][b], en);
        if (cv < v0[a]) { v1[a] = v0[a]; i1[a] = i0[a]; v0[a] = cv; i0[a] = k; }
        else if (cv < v1[a]) { v1[a] = cv; i1[a] = k; }
      }
    }
  }
#pragma unroll
  for (int j = 0; j < 8; j++) {
    int row = row0 + ty*8 + j;
    int* cr = cand + (size_t)row * 32;
    cr[tx*2 + 0] = i0[j];
    cr[tx*2 + 1] = i1[j];
  }
}

// ---------------------------------------------------------------------------
// K5: f64 exact rescore of 32 candidates -> argmin -> copy emb row to z_q.
// grid = ROWS blocks, 64 threads. z_e recomputed in f64 (matches K3 bitwise).
// ---------------------------------------------------------------------------
__global__ __launch_bounds__(64) void k5_rescore(
    const float* __restrict__ x, const float* __restrict__ w,
    const double* __restrict__ params, const float* __restrict__ emb,
    const double* __restrict__ enorm, const int* __restrict__ cand,
    float* __restrict__ zq) {
  __shared__ float xs[D + 2*PAD];
  __shared__ double ze[D];
  const int rid = blockIdx.x;
  const int b = rid >> 10;          // /(C*H)
  const int c = (rid >> 6) & 15;
  const int h = rid & 63;
  const int tid = threadIdx.x;      // 64
  const float* xrow = x + ((size_t)(b*H + h)) * D;
  for (int i = tid; i < D; i += 64) xs[i + PAD] = xrow[i];
  if (tid < PAD) { xs[tid] = 0.f; xs[D + PAD + tid] = 0.f; }
  __syncthreads();
  double wreg[T];
#pragma unroll
  for (int t = 0; t < T; t++) wreg[t] = (double)w[c*T + t];
  const double a = params[c*4+2], bb = params[c*4+3];
  for (int i = tid; i < D; i += 64) {
    double z = 0.0;
#pragma unroll
    for (int t = 0; t < T; t++) z = fma(wreg[t], (double)xs[i + t], z);
    ze[i] = fma(a, z, bb);
  }
  __syncthreads();
  double bestv = 1e300; int bestk = K;
  const int* cr = cand + (size_t)rid * 32;
  for (int j = 0; j < 32; j++) {
    int k = cr[j];
    const float* er = emb + (size_t)k * D;
    double dot = 0.0;
    for (int i = tid; i < D; i += 64) dot = fma(ze[i], (double)er[i], dot);
#pragma unroll
    for (int off = 32; off; off >>= 1) dot += __shfl_down(dot, off, 64);
    dot = __shfl(dot, 0, 64);
    double cv = enorm[k] - 2.0 * dot;
    if (cv < bestv || (cv == bestv && k < bestk)) { bestv = cv; bestk = k; }
  }
  const float* er = emb + (size_t)bestk * D;
  float* zr = zq + (size_t)rid * D;
  for (int i = tid; i < D; i += 64) zr[i] = er[i];
}

// ---------------------------------------------------------------------------
// K7: decoder (transposed conv == conv with flipped kernel) + tanh.
// grid = BH blocks, 256 threads (one per d)
// ---------------------------------------------------------------------------
__global__ __launch_bounds__(256) void k7_decode(
    const float* __restrict__ zq, const float* __restrict__ wdec,
    float* __restrict__ xt) {
  __shared__ float zs[C][D + 2*PAD];
  __shared__ float wt[C*T];
  const int bh = blockIdx.x;
  const int b = bh >> 6, h = bh & 63;
  const int tid = threadIdx.x;
  if (tid < C*T) { int c = tid / T, t = tid % T; wt[c*T + t] = wdec[c*T + (T-1-t)]; }
  for (int i = tid; i < C*D; i += 256) {
    int c = i >> 8, d = i & 255;
    zs[c][d + PAD] = zq[((size_t)(b*C*H + c*H + h)) * D + d];
  }
  if (tid < C*2*PAD) {
    int c = tid / (2*PAD), j = tid % (2*PAD);
    zs[c][j < PAD ? j : (D + PAD + (j - PAD))] = 0.f;
  }
  __syncthreads();
  const int d = tid;
  double p = 0.0;
#pragma unroll
  for (int c = 0; c < C; c++)
#pragma unroll
    for (int t = 0; t < T; t++)
      p = fma((double)wt[c*T + t], (double)zs[c][d + t], p);
  xt[(size_t)bh * D + d] = (float)tanh(p);
}

// ---------------------------------------------------------------------------
extern "C" void kernel_launch(void* const* d_in, const int* in_sizes, int n_in,
                              void* d_out, int out_size, void* d_ws, size_t ws_size,
                              hipStream_t stream) {
  const float* x     = (const float*)d_in[0];
  const float* w_enc = (const float*)d_in[1];
  const float* gamma = (const float*)d_in[2];
  const float* beta  = (const float*)d_in[3];
  const float* emb   = (const float*)d_in[4];
  const float* w_dec = (const float*)d_in[5];

  float* out = (float*)d_out;
  float* xt = out;                                    // 524288
  float* zE = out + (size_t)B*H*D;                    // 8388608
  float* zq = out + (size_t)B*H*D + (size_t)B*C*H*D;  // 8388608

  char* ws = (char*)d_ws;
  double* partial = (double*)(ws);                    // 2048*16*2*8 = 524288 B
  double* params  = (double*)(ws + 524288);           // 16*4*8      = 512 B
  double* enorm   = (double*)(ws + 524800);           // 2048*8      = 16384 B
  float*  enormf  = (float*) (ws + 541184);           // 2048*4      = 8192 B
  int*    cand    = (int*)   (ws + 549376);           // 32768*32*4  = 4 MiB

  k1_conv_stats<<<BH, 256, 0, stream>>>(x, w_enc, partial);
  k2_stats_final<<<C, 256, 0, stream>>>(partial, gamma, beta, params);
  k6_enorm<<<K, 64, 0, stream>>>(emb, enorm, enormf);
  k3_ze<<<BH, 256, 0, stream>>>(x, w_enc, params, zE);
  k4_phaseA<<<ROWS/128, 256, 0, stream>>>(zE, emb, enormf, cand);
  k5_rescore<<<ROWS, 64, 0, stream>>>(x, w_enc, params, emb, enorm, cand, zq);
  k7_decode<<<BH, 256, 0, stream>>>(zq, w_dec, xt);
}

// Round 2
// 272.987 us; speedup vs baseline: 5.3213x; 5.3213x over previous
//
#include <hip/hip_runtime.h>
#include <hip/hip_bf16.h>
#include <cstddef>

// Problem constants
#define B   32
#define C   16
#define H   64
#define D   256
#define K   2048
#define T   15
#define PAD 7
#define EPS 1e-5

#define BH      (B*H)       // 2048
#define ROWS    (B*C*H)     // 32768 VQ rows
#define N_PER_CH ((double)(B*H*D)) // 524288
#define NC  8               // candidates per row after merge

typedef __attribute__((ext_vector_type(8))) short bf16x8;
typedef __attribute__((ext_vector_type(4))) float f32x4;

__device__ __forceinline__ void gload_lds16(const void* g, void* l) {
  __builtin_amdgcn_global_load_lds(
      (const __attribute__((address_space(1))) unsigned int*)g,
      (__attribute__((address_space(3))) unsigned int*)l, 16, 0, 0);
}

// ---------------------------------------------------------------------------
// K1: encoder conv (f64) + per-block partial sums for BN stats (deterministic)
// ---------------------------------------------------------------------------
__global__ __launch_bounds__(256) void k1_conv_stats(
    const float* __restrict__ x, const float* __restrict__ w,
    double* __restrict__ partial /* [BH][C][2] */) {
  __shared__ float xs[D + 2*PAD];
  __shared__ float wsm[C*T];
  __shared__ double red[4][C][2];
  const int bh  = blockIdx.x;
  const int tid = threadIdx.x;
  const float* xrow = x + (size_t)bh * D;
  if (tid < C*T) wsm[tid] = w[tid];
  xs[tid + PAD] = xrow[tid];
  if (tid < PAD) { xs[tid] = 0.f; xs[tid + PAD + D] = 0.f; }
  __syncthreads();
  const int d = tid;
#pragma unroll
  for (int c = 0; c < C; c++) {
    double z = 0.0;
#pragma unroll
    for (int t = 0; t < T; t++)
      z = fma((double)wsm[c*T + t], (double)xs[d + t], z);
    double zz = z * z;
#pragma unroll
    for (int off = 32; off; off >>= 1) {
      z  += __shfl_down(z,  off, 64);
      zz += __shfl_down(zz, off, 64);
    }
    if ((tid & 63) == 0) { red[tid >> 6][c][0] = z; red[tid >> 6][c][1] = zz; }
  }
  __syncthreads();
  if (tid < C*2) {
    int c = tid >> 1, j = tid & 1;
    double v = red[0][c][j] + red[1][c][j] + red[2][c][j] + red[3][c][j];
    partial[(size_t)bh * (C*2) + c*2 + j] = v;
  }
}

// ---------------------------------------------------------------------------
// K2: finalize BN per-channel params (deterministic tree)
// ---------------------------------------------------------------------------
__global__ __launch_bounds__(256) void k2_stats_final(
    const double* __restrict__ partial, const float* __restrict__ gamma,
    const float* __restrict__ beta, double* __restrict__ params) {
  __shared__ double rs[256], rq[256];
  const int c = blockIdx.x;
  const int tid = threadIdx.x;
  double s = 0.0, q = 0.0;
  for (int i = tid; i < BH; i += 256) {
    s += partial[(size_t)i * (C*2) + c*2 + 0];
    q += partial[(size_t)i * (C*2) + c*2 + 1];
  }
  rs[tid] = s; rq[tid] = q;
  __syncthreads();
  for (int off = 128; off; off >>= 1) {
    if (tid < off) { rs[tid] += rs[tid + off]; rq[tid] += rq[tid + off]; }
    __syncthreads();
  }
  if (tid == 0) {
    double m = rs[0] / N_PER_CH;
    double v = rq[0] / N_PER_CH - m * m;
    double a = (double)gamma[c] / sqrt(v + EPS);
    double b = (double)beta[c] - a * m;
    params[c*4+0] = m; params[c*4+1] = v; params[c*4+2] = a; params[c*4+3] = b;
  }
}

// ---------------------------------------------------------------------------
// K6: ||e_k||^2 in f64 (+f32 copy) + bf16 copy of emb. grid=K, 64 thr
// ---------------------------------------------------------------------------
__global__ __launch_bounds__(64) void k6_enorm(
    const float* __restrict__ emb, double* __restrict__ enorm,
    float* __restrict__ enormf, __hip_bfloat16* __restrict__ embB) {
  const int k = blockIdx.x;
  const int tid = threadIdx.x;
  const float* er = emb + (size_t)k * D;
  double s = 0.0;
  for (int i = tid; i < D; i += 64) {
    float e = er[i];
    embB[(size_t)k * D + i] = __float2bfloat16(e);
    double ed = (double)e;
    s = fma(ed, ed, s);
  }
#pragma unroll
  for (int off = 32; off; off >>= 1) s += __shfl_down(s, off, 64);
  if (tid == 0) { enorm[k] = s; enormf[k] = (float)s; }
}

// ---------------------------------------------------------------------------
// K3: recompute conv (f64) + affine -> z_e (f32) + z_e bf16 copy
// ---------------------------------------------------------------------------
__global__ __launch_bounds__(256) void k3_ze(
    const float* __restrict__ x, const float* __restrict__ w,
    const double* __restrict__ params, float* __restrict__ zE,
    __hip_bfloat16* __restrict__ zEb) {
  __shared__ float xs[D + 2*PAD];
  __shared__ float wsm[C*T];
  const int bh  = blockIdx.x;
  const int b = bh >> 6, h = bh & 63;
  const int tid = threadIdx.x;
  const float* xrow = x + (size_t)bh * D;
  if (tid < C*T) wsm[tid] = w[tid];
  xs[tid + PAD] = xrow[tid];
  if (tid < PAD) { xs[tid] = 0.f; xs[tid + PAD + D] = 0.f; }
  __syncthreads();
  const int d = tid;
#pragma unroll
  for (int c = 0; c < C; c++) {
    double z = 0.0;
#pragma unroll
    for (int t = 0; t < T; t++)
      z = fma((double)wsm[c*T + t], (double)xs[d + t], z);
    double ze = fma(params[c*4+2], z, params[c*4+3]);
    float zf = (float)ze;
    size_t idx = (((size_t)b*C + c)*H + h)*D + d;
    zE[idx] = zf;
    zEb[idx] = __float2bfloat16(zf);
  }
}

// ---------------------------------------------------------------------------
// K4: MFMA phase-A. Block = 64 rows x full N loop. 256 thr = 4 waves (2x2).
// A resident in LDS as [kstep][64][32] panels; B 4-slot ring, counted vmcnt.
// Fused criterion + per-lane top-2 trackers -> per-row top-8 merge -> cand.
// ---------------------------------------------------------------------------
#define MT 64
#define BK 32
#define KSTEPS 8     // 256/32
#define NTILES 16    // 2048/128

__global__ __launch_bounds__(256) void k4_mfma(
    const __hip_bfloat16* __restrict__ zEb, const __hip_bfloat16* __restrict__ embB,
    const float* __restrict__ enormf, int* __restrict__ cand /*[ROWS][NC]*/) {
  __shared__ __attribute__((aligned(16))) __hip_bfloat16 Ash[KSTEPS][MT][BK]; // 32 KB
  __shared__ __attribute__((aligned(16))) __hip_bfloat16 Bsh[4][128][BK];     // 32 KB
  __shared__ __attribute__((aligned(16))) float Ensh[K];                      // 8 KB

  const int tid = threadIdx.x;
  const int w = tid >> 6, lane = tid & 63;
  const int wr = w >> 1, wc = w & 1;
  const int l15 = lane & 15, l4 = lane >> 4;
  const int row0 = blockIdx.x * MT;

  // ---- prologue staging ----
#pragma unroll
  for (int i = 0; i < 8; i++) {            // A: 2048 chunks of 16B
    int p = i*256 + tid;
    int kq = p & 3, r = (p >> 2) & 63, kk = p >> 8;
    gload_lds16(zEb + (((size_t)(row0 + r)) << 8) + kk*BK + kq*8, &Ash[kk][r][kq*8]);
  }
#pragma unroll
  for (int j = 0; j < 2; j++) {            // enormf: 512 chunks
    int p = j*256 + tid;
    gload_lds16(enormf + p*4, &Ensh[p*4]);
  }
  auto stageB = [&](int s) {               // s = global step index (wrapped)
    const int snt = s >> 3, skk = s & 7, sb = s & 3;
#pragma unroll
    for (int j = 0; j < 2; j++) {
      int p = j*256 + tid;
      int r = p >> 2, kq = p & 3;
      gload_lds16(embB + (((size_t)(snt*128 + r)) << 8) + skk*BK + kq*8,
                  &Bsh[sb][r][kq*8]);
    }
  };
  stageB(0); stageB(1); stageB(2);
  asm volatile("s_waitcnt vmcnt(4) lgkmcnt(0)" ::: "memory"); // A,En,B0 done
  __builtin_amdgcn_sched_barrier(0);
  __builtin_amdgcn_s_barrier();

  // trackers: 8 row-slots (a*4+reg), top-2 each, idx packed u16x2
  float tv0[8], tv1[8]; unsigned ti[8];
#pragma unroll
  for (int s = 0; s < 8; s++) { tv0[s] = 3.0e38f; tv1[s] = 3.0e38f; ti[s] = 0; }

  for (int nt = 0; nt < NTILES; nt++) {
    f32x4 acc[2][4];
#pragma unroll
    for (int a = 0; a < 2; a++)
#pragma unroll
      for (int b = 0; b < 4; b++) acc[a][b] = (f32x4){0.f, 0.f, 0.f, 0.f};

    for (int kk = 0; kk < KSTEPS; kk++) {
      const int t = nt*KSTEPS + kk;
      const int buf = t & 3;
      bf16x8 af[2], bfr[4];
#pragma unroll
      for (int a = 0; a < 2; a++)
        af[a] = *(const bf16x8*)&Ash[kk][wr*32 + a*16 + l15][l4*8];
#pragma unroll
      for (int b = 0; b < 4; b++)
        bfr[b] = *(const bf16x8*)&Bsh[buf][wc*64 + b*16 + l15][l4*8];
      stageB((t + 3) & 127);               // prefetch depth 3 (wraps harmlessly)
#pragma unroll
      for (int a = 0; a < 2; a++)
#pragma unroll
        for (int b = 0; b < 4; b++)
          acc[a][b] = __builtin_amdgcn_mfma_f32_16x16x32_bf16(af[a], bfr[b], acc[a][b], 0, 0, 0);
      // own reads serviced + stage(t+1) landed, before common barrier
      asm volatile("s_waitcnt vmcnt(4) lgkmcnt(0)" ::: "memory");
      __builtin_amdgcn_sched_barrier(0);
      __builtin_amdgcn_s_barrier();
    }

    // criterion + tracker update (registers + Ensh only)
#pragma unroll
    for (int b = 0; b < 4; b++) {
      const int col = nt*128 + wc*64 + b*16 + l15;
      const float en = Ensh[col];
#pragma unroll
      for (int a = 0; a < 2; a++) {
        const f32x4 v = acc[a][b];
#pragma unroll
        for (int r = 0; r < 4; r++) {
          const float cv = fmaf(-2.f, v[r], en);
          const int s = a*4 + r;
          if (cv < tv0[s]) { tv1[s] = tv0[s]; tv0[s] = cv; ti[s] = (ti[s] << 16) | (unsigned)col; }
          else if (cv < tv1[s]) { tv1[s] = cv; ti[s] = (ti[s] & 0xFFFFu) | ((unsigned)col << 16); }
        }
      }
    }
  }

  // ---- merge 32 trackers x top-2 -> top-8 per row ----
  __syncthreads();                         // full drain (wrapped stages too)
  float* Vals = (float*)Ash;               // [64 entries][64 rows] = 16 KB
  unsigned* IdxP = (unsigned*)(Vals + 64*64); // [32 trackers][64 rows] = 8 KB
  const int tk = wc*16 + l15;
#pragma unroll
  for (int s = 0; s < 8; s++) {
    const int r = wr*32 + (s >> 2)*16 + l4*4 + (s & 3);
    Vals[(tk*2 + 0)*64 + r] = tv0[s];
    Vals[(tk*2 + 1)*64 + r] = tv1[s];
    IdxP[tk*64 + r] = ti[s];
  }
  __syncthreads();
  if (tid < MT) {
    const int r = tid;
    float bv[NC]; int bi[NC];
#pragma unroll
    for (int j = 0; j < NC; j++) { bv[j] = 3.0e38f; bi[j] = 0; }
    for (int e = 0; e < 64; e++) {
      float v = Vals[e*64 + r];
      unsigned pp = IdxP[(e >> 1)*64 + r];
      int idx = (e & 1) ? (int)(pp >> 16) : (int)(pp & 0xFFFFu);
      if (v < bv[NC-1]) {
        int j = NC-1;
        while (j > 0 && v < bv[j-1]) { bv[j] = bv[j-1]; bi[j] = bi[j-1]; j--; }
        bv[j] = v; bi[j] = idx;
      }
    }
    int* cr = cand + ((size_t)(row0 + r)) * NC;
#pragma unroll
    for (int j = 0; j < NC; j++) cr[j] = bi[j];
  }
}

// ---------------------------------------------------------------------------
// K5: f64 exact rescore of NC candidates -> argmin -> copy emb row to z_q
// ---------------------------------------------------------------------------
__global__ __launch_bounds__(64) void k5_rescore(
    const float* __restrict__ x, const float* __restrict__ w,
    const double* __restrict__ params, const float* __restrict__ emb,
    const double* __restrict__ enorm, const int* __restrict__ cand,
    float* __restrict__ zq) {
  __shared__ float xs[D + 2*PAD];
  __shared__ double ze[D];
  const int rid = blockIdx.x;
  const int b = rid >> 10;
  const int c = (rid >> 6) & 15;
  const int h = rid & 63;
  const int tid = threadIdx.x;
  const float* xrow = x + ((size_t)(b*H + h)) * D;
  for (int i = tid; i < D; i += 64) xs[i + PAD] = xrow[i];
  if (tid < PAD) { xs[tid] = 0.f; xs[D + PAD + tid] = 0.f; }
  __syncthreads();
  double wreg[T];
#pragma unroll
  for (int t = 0; t < T; t++) wreg[t] = (double)w[c*T + t];
  const double a = params[c*4+2], bb = params[c*4+3];
  for (int i = tid; i < D; i += 64) {
    double z = 0.0;
#pragma unroll
    for (int t = 0; t < T; t++) z = fma(wreg[t], (double)xs[i + t], z);
    ze[i] = fma(a, z, bb);
  }
  __syncthreads();
  double bestv = 1e300; int bestk = K;
  const int* cr = cand + (size_t)rid * NC;
  for (int j = 0; j < NC; j++) {
    int k = cr[j];
    const float* er = emb + (size_t)k * D;
    double dot = 0.0;
    for (int i = tid; i < D; i += 64) dot = fma(ze[i], (double)er[i], dot);
#pragma unroll
    for (int off = 32; off; off >>= 1) dot += __shfl_down(dot, off, 64);
    dot = __shfl(dot, 0, 64);
    double cv = enorm[k] - 2.0 * dot;
    if (cv < bestv || (cv == bestv && k < bestk)) { bestv = cv; bestk = k; }
  }
  const float* er = emb + (size_t)bestk * D;
  float* zr = zq + (size_t)rid * D;
  for (int i = tid; i < D; i += 64) zr[i] = er[i];
}

// ---------------------------------------------------------------------------
// K7: decoder (transposed conv == conv with flipped kernel) + tanh
// ---------------------------------------------------------------------------
__global__ __launch_bounds__(256) void k7_decode(
    const float* __restrict__ zq, const float* __restrict__ wdec,
    float* __restrict__ xt) {
  __shared__ float zs[C][D + 2*PAD];
  __shared__ float wt[C*T];
  const int bh = blockIdx.x;
  const int b = bh >> 6, h = bh & 63;
  const int tid = threadIdx.x;
  if (tid < C*T) { int c = tid / T, t = tid % T; wt[c*T + t] = wdec[c*T + (T-1-t)]; }
  for (int i = tid; i < C*D; i += 256) {
    int c = i >> 8, d = i & 255;
    zs[c][d + PAD] = zq[((size_t)(b*C*H + c*H + h)) * D + d];
  }
  if (tid < C*2*PAD) {
    int c = tid / (2*PAD), j = tid % (2*PAD);
    zs[c][j < PAD ? j : (D + PAD + (j - PAD))] = 0.f;
  }
  __syncthreads();
  const int d = tid;
  double p = 0.0;
#pragma unroll
  for (int c = 0; c < C; c++)
#pragma unroll
    for (int t = 0; t < T; t++)
      p = fma((double)wt[c*T + t], (double)zs[c][d + t], p);
  xt[(size_t)bh * D + d] = (float)tanh(p);
}

// ---------------------------------------------------------------------------
extern "C" void kernel_launch(void* const* d_in, const int* in_sizes, int n_in,
                              void* d_out, int out_size, void* d_ws, size_t ws_size,
                              hipStream_t stream) {
  const float* x     = (const float*)d_in[0];
  const float* w_enc = (const float*)d_in[1];
  const float* gamma = (const float*)d_in[2];
  const float* beta  = (const float*)d_in[3];
  const float* emb   = (const float*)d_in[4];
  const float* w_dec = (const float*)d_in[5];

  float* out = (float*)d_out;
  float* xt = out;                                    // 524288
  float* zE = out + (size_t)B*H*D;                    // 8388608
  float* zq = out + (size_t)B*H*D + (size_t)B*C*H*D;  // 8388608

  char* ws = (char*)d_ws;
  double* partial = (double*)(ws);                       // 524288 B
  double* params  = (double*)(ws + 524288);              // 512 B
  double* enorm   = (double*)(ws + 524800);              // 16384 B
  float*  enormf  = (float*) (ws + 541184);              // 8192 B
  int*    cand    = (int*)   (ws + 549376);              // 32768*8*4 = 1 MiB
  __hip_bfloat16* zEb  = (__hip_bfloat16*)(ws + 1597952);   // 16 MiB
  __hip_bfloat16* embB = (__hip_bfloat16*)(ws + 18375168);  // 1 MiB

  k1_conv_stats<<<BH, 256, 0, stream>>>(x, w_enc, partial);
  k2_stats_final<<<C, 256, 0, stream>>>(partial, gamma, beta, params);
  k6_enorm<<<K, 64, 0, stream>>>(emb, enorm, enormf, embB);
  k3_ze<<<BH, 256, 0, stream>>>(x, w_enc, params, zE, zEb);
  k4_mfma<<<ROWS/MT, 256, 0, stream>>>(zEb, embB, enormf, cand);
  k5_rescore<<<ROWS, 64, 0, stream>>>(x, w_enc, params, emb, enorm, cand, zq);
  k7_decode<<<BH, 256, 0, stream>>>(zq, w_dec, xt);
}